// Round 1
// baseline (2114.685 us; speedup 1.0000x reference)
//
#include <hip/hip_runtime.h>

// GPTQ 4-bit fused dequant GEMM: out[M,N] = x[M,K] @ W[K,N]
// W[k,n] = scales[k/128, n] * (nibble(qweight, k, n) - (nibble(qzeros, k/128, n) + 1))
// M = 8192, K = 4096, N = 11008, GROUP = 128.
//
// Structure: m97-style 128x128 tile, BK=32, 256 threads = 4 waves (2x2 of 64x64),
// mfma_f32_16x16x32_bf16, 4x4 acc tiles/wave. Dequant fused into B staging;
// fp32->bf16 convert fused into A staging. Scale/zero hoisted per group
// (one group spans exactly 4 K-tiles; a 32-row K-tile never crosses a group).

typedef __bf16 bf16;
typedef __attribute__((ext_vector_type(8))) __bf16 bf16x8;
typedef __attribute__((ext_vector_type(4))) __bf16 bf16x4;
typedef __attribute__((ext_vector_type(4))) float floatx4;

constexpr int BM = 128, BN = 128, BK = 32;
constexpr int LDT = 40;   // LDS leading stride in bf16 elems: 80 B, 16B-aligned for b128
constexpr int KDIM = 4096;
constexpr int NDIM = 11008;
constexpr int GROUP = 128;

__global__ __launch_bounds__(256)
void gptq_gemm(const float* __restrict__ x, const int* __restrict__ qweight,
               const int* __restrict__ qzeros, const float* __restrict__ scales,
               float* __restrict__ out) {
  __shared__ bf16 As[BM * LDT];
  __shared__ bf16 Bs[BN * LDT];

  const int tid  = threadIdx.x;
  const int lane = tid & 63;
  const int wave = tid >> 6;
  const int quad = lane >> 4;
  const int l16  = lane & 15;
  const int wm   = (wave >> 1) * 64;   // wave's m-origin in tile
  const int wn   = (wave & 1) * 64;    // wave's n-origin in tile

  const int row0 = blockIdx.y * BM;
  const int col0 = blockIdx.x * BN;

  // B staging assignment: each thread owns one column nb and packed-rows {kpl0, kpl0+2}
  const int nb   = tid & 127;
  const int kpl0 = tid >> 7;           // 0 or 1
  const int gn   = col0 + nb;          // global column this thread stages

  floatx4 acc[4][4];
#pragma unroll
  for (int i = 0; i < 4; ++i)
#pragma unroll
    for (int j = 0; j < 4; ++j) acc[i][j] = (floatx4)0.f;

  const int NGROUPS = KDIM / GROUP;    // 32

  for (int g = 0; g < NGROUPS; ++g) {
    // hoisted per-group dequant constants for this thread's column
    const float sc = scales[g * NDIM + gn];
    const unsigned int zw = (unsigned int)qzeros[g * (NDIM / 8) + (gn >> 3)];
    const int z = (int)((zw >> ((gn & 7) * 4)) & 0xF) + 1;
    const float zs = (float)z * sc;

    for (int kk = 0; kk < GROUP / BK; ++kk) {   // 4 K-tiles per group
      const int k0 = g * GROUP + kk * BK;

      // ---- stage A: 128x32 fp32 -> bf16 (k-contiguous rows) ----
#pragma unroll
      for (int r = 0; r < 4; ++r) {
        const int flat = r * 256 + tid;       // 0..1023 float4s
        const int m  = flat >> 3;             // row in tile
        const int k4 = (flat & 7) << 2;       // col (float) in tile
        const float4 v = *(const float4*)&x[(row0 + m) * KDIM + k0 + k4];
        bf16x4 pk = { (bf16)v.x, (bf16)v.y, (bf16)v.z, (bf16)v.w };
        *(bf16x4*)&As[m * LDT + k4] = pk;
      }

      // ---- stage B: 4 packed rows x 128 cols, dequant int4 -> bf16 ----
      const int kp0 = k0 >> 3;                // packed-row base
#pragma unroll
      for (int w = 0; w < 2; ++w) {
        const int kpl = kpl0 + w * 2;         // 0..3
        const unsigned int word = (unsigned int)qweight[(kp0 + kpl) * NDIM + gn];
        bf16x8 pk;
#pragma unroll
        for (int j = 0; j < 8; ++j) {
          const float q = (float)((word >> (4 * j)) & 0xF);
          pk[j] = (bf16)(q * sc - zs);        // = sc * (q - z)
        }
        // XOR-swizzle 16B sub-blocks to break the 8-way write conflict at stride 40
        const int sw = kpl ^ ((nb >> 3) & 3);
        *(bf16x8*)&Bs[nb * LDT + sw * 8] = pk;
      }

      __syncthreads();

      // ---- compute: 16 MFMAs per wave ----
      bf16x8 af[4], bfr[4];
#pragma unroll
      for (int i = 0; i < 4; ++i)
        af[i] = *(bf16x8*)&As[(wm + i * 16 + l16) * LDT + quad * 8];
#pragma unroll
      for (int j = 0; j < 4; ++j) {
        const int nr = wn + j * 16 + l16;
        const int sw = quad ^ ((nr >> 3) & 3);
        bfr[j] = *(bf16x8*)&Bs[nr * LDT + sw * 8];
      }
#pragma unroll
      for (int i = 0; i < 4; ++i)
#pragma unroll
        for (int j = 0; j < 4; ++j)
          acc[i][j] = __builtin_amdgcn_mfma_f32_16x16x32_bf16(af[i], bfr[j], acc[i][j], 0, 0, 0);

      __syncthreads();
    }
  }

  // ---- epilogue: C/D layout col=lane&15, row=quad*4+reg (m89-verified) ----
#pragma unroll
  for (int i = 0; i < 4; ++i) {
#pragma unroll
    for (int j = 0; j < 4; ++j) {
      const int r0 = row0 + wm + i * 16 + quad * 4;
      const int c  = col0 + wn + j * 16 + l16;
#pragma unroll
      for (int r = 0; r < 4; ++r)
        out[(r0 + r) * NDIM + c] = acc[i][j][r];
    }
  }
}

extern "C" void kernel_launch(void* const* d_in, const int* in_sizes, int n_in,
                              void* d_out, int out_size, void* d_ws, size_t ws_size,
                              hipStream_t stream) {
  const float* x        = (const float*)d_in[0];
  const int*   qweight  = (const int*)d_in[1];
  const int*   qzeros   = (const int*)d_in[2];
  const float* scales   = (const float*)d_in[3];
  float*       out      = (float*)d_out;

  const int M = in_sizes[0] / KDIM;          // 8192
  dim3 grid(NDIM / BN, M / BM);              // (86, 64)
  gptq_gemm<<<grid, 256, 0, stream>>>(x, qweight, qzeros, scales, out);
}